// Round 5
// baseline (483.422 us; speedup 1.0000x reference)
//
#include <hip/hip_runtime.h>
#include <math.h>

// ---------------- problem constants (match reference) ----------------
// N=50000, F_IN=128, HID=64, HEADS1=4 (C1=256), NUM_GRAPHS=64, slope=0.2

typedef unsigned short ushort_t;

__device__ inline float bf2f(ushort_t u) { return __uint_as_float((unsigned)u << 16); }
__device__ inline ushort_t f2bf(float x) {            // round-to-nearest-even
  unsigned b = __float_as_uint(x);
  return (ushort_t)((b + 0x7fff + ((b >> 16) & 1)) >> 16);
}
__device__ inline float leaky(float v) { return (v > 0.f) ? v : 0.2f * v; }

// ---------------- small utility kernels ----------------
__global__ void k_zero_i32(int* __restrict__ p, int n) {
  int i = blockIdx.x * blockDim.x + threadIdx.x;
  if (i < n) p[i] = 0;
}

__global__ void k_hist(const int* __restrict__ edst, int E, int N, int* __restrict__ deg) {
  int stride = gridDim.x * blockDim.x;
  int EE = E + N;
  for (int i = blockIdx.x * blockDim.x + threadIdx.x; i < EE; i += stride) {
    int d = (i < E) ? edst[i] : (i - E);
    atomicAdd(&deg[d], 1);
  }
}

// graph boundaries from SORTED batch array -> gstart[0..G], no atomics
__global__ void k_gbounds(const int* __restrict__ batch, int N, int G,
                          int* __restrict__ gstart) {
  int stride = gridDim.x * blockDim.x;
  for (int i = blockIdx.x * blockDim.x + threadIdx.x; i < N; i += stride) {
    int b = batch[i];
    int bp = (i == 0) ? -1 : batch[i - 1];
    for (int g = bp + 1; g <= b; ++g) gstart[g] = i;
    if (i == N - 1)
      for (int g = b + 1; g <= G; ++g) gstart[g] = N;
  }
}

// single-block exclusive scan; wave-shfl scan + cross-wave LDS, 2 barriers/chunk
__global__ void k_scan(const int* __restrict__ deg, int n,
                       int* __restrict__ offsets, int* __restrict__ cursor) {
  __shared__ int wsum[16];
  __shared__ int carry_s;
  int tid = threadIdx.x, lane = tid & 63, wv = tid >> 6;
  if (tid == 0) carry_s = 0;
  __syncthreads();
  for (int base = 0; base < n; base += 1024) {
    int i = base + tid;
    int v = (i < n) ? deg[i] : 0;
    int x = v;
    #pragma unroll
    for (int off = 1; off < 64; off <<= 1) {
      int t = __shfl_up(x, off);
      if (lane >= off) x += t;
    }
    if (lane == 63) wsum[wv] = x;
    __syncthreads();
    if (wv == 0 && lane < 16) {
      int s = wsum[lane];
      #pragma unroll
      for (int off = 1; off < 16; off <<= 1) {
        int t = __shfl_up(s, off);
        if (lane >= off) s += t;
      }
      wsum[lane] = s;
    }
    __syncthreads();
    int wbase = (wv == 0) ? 0 : wsum[wv - 1];
    int incl = carry_s + wbase + x;
    if (i < n) { int o = incl - v; offsets[i] = o; cursor[i] = o; }
    __syncthreads();
    if (tid == 1023) carry_s = incl;
    __syncthreads();
  }
  if (tid == 0) offsets[n] = carry_s;
}

__global__ void k_scatter(const int* __restrict__ esrc, const int* __restrict__ edst,
                          int E, int N, int* __restrict__ cursor, int* __restrict__ ssrc) {
  int stride = gridDim.x * blockDim.x;
  int EE = E + N;
  for (int i = blockIdx.x * blockDim.x + threadIdx.x; i < EE; i += stride) {
    int d, s;
    if (i < E) { d = edst[i]; s = esrc[i]; }
    else       { d = i - E;   s = i - E;   }
    int pos = atomicAdd(&cursor[d], 1);
    ssrc[pos] = s;
  }
}

// ---------------- fused f32 GEMM + attention logits + bf16 output ----------------
// C = A[M,K] @ B[K,Nn]; tile 128x64, 8x4 microtile, K-step 32, double-buffered LDS,
// one barrier per K-step. Epilogue: per-row head-local dots with a_src/a_dst
// (width-16 shfl reduce), writes bf16 h + as/ad. No f32 C is materialized.
// Each 64-col block is one head (Nn = H*64, col0 = head*64).
__global__ __launch_bounds__(256)
void k_gemm_att(const float* __restrict__ A, const float* __restrict__ B,
                const float* __restrict__ a_srcW, const float* __restrict__ a_dstW,
                ushort_t* __restrict__ hb, float* __restrict__ as_,
                float* __restrict__ ad_, int M, int Nn, int K, int H) {
  __shared__ float As[2][32][132];   // [kk][row], pad 132: aligned b128, ~4-way wr
  __shared__ float Bs[2][32][68];    // [kk][col], pad 68: 2-way rd (free)
  const int tid = threadIdx.x;
  const int tx = tid & 15, ty = tid >> 4;
  const int row0 = blockIdx.x * 128, col0 = blockIdx.y * 64;
  const int head = col0 >> 6;

  float acc[8][4] = {};
  float4 ra[4], rb[2];

  auto gload = [&](int k0) {
    #pragma unroll
    for (int p = 0; p < 4; ++p) {
      int r = (tid >> 3) + p * 32;
      int kk = (tid & 7) << 2;
      int gr = row0 + r;
      ra[p] = (gr < M) ? *(const float4*)(A + (size_t)gr * K + k0 + kk)
                       : make_float4(0.f, 0.f, 0.f, 0.f);
    }
    #pragma unroll
    for (int p = 0; p < 2; ++p) {
      int kk = (tid >> 4) + p * 16;
      int c = (tid & 15) << 2;
      rb[p] = *(const float4*)(B + (size_t)(k0 + kk) * Nn + col0 + c);
    }
  };
  auto swrite = [&](int b) {
    #pragma unroll
    for (int p = 0; p < 4; ++p) {
      int r = (tid >> 3) + p * 32;
      int kk = (tid & 7) << 2;
      As[b][kk + 0][r] = ra[p].x;
      As[b][kk + 1][r] = ra[p].y;
      As[b][kk + 2][r] = ra[p].z;
      As[b][kk + 3][r] = ra[p].w;
    }
    #pragma unroll
    for (int p = 0; p < 2; ++p) {
      int kk = (tid >> 4) + p * 16;
      int c = (tid & 15) << 2;
      *(float4*)&Bs[b][kk][c] = rb[p];
    }
  };

  gload(0); swrite(0); __syncthreads();
  const int T = K >> 5;
  for (int t = 0; t < T; ++t) {
    if (t + 1 < T) gload((t + 1) << 5);
    const int cur = t & 1;
    #pragma unroll
    for (int kk = 0; kk < 32; ++kk) {
      float a[8], bq[4];
      *(float4*)&a[0] = *(const float4*)&As[cur][kk][ty * 8];
      *(float4*)&a[4] = *(const float4*)&As[cur][kk][ty * 8 + 4];
      *(float4*)&bq[0] = *(const float4*)&Bs[cur][kk][tx * 4];
      #pragma unroll
      for (int i = 0; i < 8; ++i)
        #pragma unroll
        for (int j = 0; j < 4; ++j)
          acc[i][j] += a[i] * bq[j];
    }
    if (t + 1 < T) swrite((t + 1) & 1);
    __syncthreads();
  }

  // epilogue: bf16 store + per-head attention logits
  float4 sv = *(const float4*)(a_srcW + head * 64 + tx * 4);
  float4 dv = *(const float4*)(a_dstW + head * 64 + tx * 4);
  #pragma unroll
  for (int i = 0; i < 8; ++i) {
    int gr = row0 + ty * 8 + i;
    float ps = acc[i][0] * sv.x + acc[i][1] * sv.y + acc[i][2] * sv.z + acc[i][3] * sv.w;
    float pd = acc[i][0] * dv.x + acc[i][1] * dv.y + acc[i][2] * dv.z + acc[i][3] * dv.w;
    #pragma unroll
    for (int off = 1; off < 16; off <<= 1) {
      ps += __shfl_xor(ps, off);
      pd += __shfl_xor(pd, off);
    }
    if (gr < M) {
      ushort4 hv;
      hv.x = f2bf(acc[i][0]); hv.y = f2bf(acc[i][1]);
      hv.z = f2bf(acc[i][2]); hv.w = f2bf(acc[i][3]);
      *(ushort4*)(hb + (size_t)gr * Nn + col0 + tx * 4) = hv;
      if (tx == 0) { as_[gr * H + head] = ps; ad_[gr * H + head] = pd; }
    }
  }
}

// ---------------- layer-1 segment softmax + aggregation ----------------
__global__ void k_agg1(const ushort_t* __restrict__ h1b, const float* __restrict__ as1,
                       const float* __restrict__ ad1, const int* __restrict__ offs,
                       const int* __restrict__ ssrc, const float* __restrict__ b1,
                       float* __restrict__ hrelu, int N) {
  int gt = blockIdx.x * blockDim.x + threadIdx.x;
  int wid = gt >> 6, lane = gt & 63;
  if (wid >= N) return;
  int head = lane >> 4, sub = lane & 15, coff = sub << 2;
  int start = offs[wid], end = offs[wid + 1];
  float ad = ad1[wid * 4 + head];

  float m = -INFINITY;
  for (int e = start + sub; e < end; e += 16) {
    int s = ssrc[e];
    m = fmaxf(m, leaky(as1[s * 4 + head] + ad));
  }
  #pragma unroll
  for (int off = 1; off < 16; off <<= 1) m = fmaxf(m, __shfl_xor(m, off));

  float denom = 0.f;
  float4 acc = make_float4(0.f, 0.f, 0.f, 0.f);
  int e = start;
  for (; e + 4 <= end; e += 4) {
    int s0 = ssrc[e], s1 = ssrc[e + 1], s2 = ssrc[e + 2], s3 = ssrc[e + 3];
    ushort4 g0 = *(const ushort4*)(h1b + (size_t)s0 * 256 + head * 64 + coff);
    ushort4 g1 = *(const ushort4*)(h1b + (size_t)s1 * 256 + head * 64 + coff);
    ushort4 g2 = *(const ushort4*)(h1b + (size_t)s2 * 256 + head * 64 + coff);
    ushort4 g3 = *(const ushort4*)(h1b + (size_t)s3 * 256 + head * 64 + coff);
    float w0 = __expf(leaky(as1[s0 * 4 + head] + ad) - m);
    float w1 = __expf(leaky(as1[s1 * 4 + head] + ad) - m);
    float w2 = __expf(leaky(as1[s2 * 4 + head] + ad) - m);
    float w3 = __expf(leaky(as1[s3 * 4 + head] + ad) - m);
    denom += (w0 + w1) + (w2 + w3);
    acc.x += w0 * bf2f(g0.x) + w1 * bf2f(g1.x) + w2 * bf2f(g2.x) + w3 * bf2f(g3.x);
    acc.y += w0 * bf2f(g0.y) + w1 * bf2f(g1.y) + w2 * bf2f(g2.y) + w3 * bf2f(g3.y);
    acc.z += w0 * bf2f(g0.z) + w1 * bf2f(g1.z) + w2 * bf2f(g2.z) + w3 * bf2f(g3.z);
    acc.w += w0 * bf2f(g0.w) + w1 * bf2f(g1.w) + w2 * bf2f(g2.w) + w3 * bf2f(g3.w);
  }
  for (; e < end; ++e) {
    int s = ssrc[e];
    float w = __expf(leaky(as1[s * 4 + head] + ad) - m);
    ushort4 g = *(const ushort4*)(h1b + (size_t)s * 256 + head * 64 + coff);
    denom += w;
    acc.x += w * bf2f(g.x); acc.y += w * bf2f(g.y);
    acc.z += w * bf2f(g.z); acc.w += w * bf2f(g.w);
  }
  float inv = 1.f / denom;
  float4 bv = *(const float4*)(b1 + head * 64 + coff);
  float4 o;
  o.x = fmaxf(acc.x * inv + bv.x, 0.f);
  o.y = fmaxf(acc.y * inv + bv.y, 0.f);
  o.z = fmaxf(acc.z * inv + bv.z, 0.f);
  o.w = fmaxf(acc.w * inv + bv.w, 0.f);
  *(float4*)(hrelu + (size_t)wid * 256 + head * 64 + coff) = o;
}

// ---------------- layer-2 segment softmax + aggregation ----------------
__global__ void k_agg2(const ushort_t* __restrict__ h2b, const float* __restrict__ as2,
                       const float* __restrict__ ad2, const int* __restrict__ offs,
                       const int* __restrict__ ssrc, const float* __restrict__ b2,
                       float* __restrict__ hfin, int N) {
  int gt = blockIdx.x * blockDim.x + threadIdx.x;
  int wid = gt >> 6, lane = gt & 63;
  if (wid >= N) return;
  int start = offs[wid], end = offs[wid + 1];
  float ad = ad2[wid];

  float m = -INFINITY;
  for (int e = start + lane; e < end; e += 64) {
    m = fmaxf(m, leaky(as2[ssrc[e]] + ad));
  }
  #pragma unroll
  for (int off = 1; off < 64; off <<= 1) m = fmaxf(m, __shfl_xor(m, off));

  float denom = 0.f, acc = 0.f;
  int e = start;
  for (; e + 4 <= end; e += 4) {
    int s0 = ssrc[e], s1 = ssrc[e + 1], s2 = ssrc[e + 2], s3 = ssrc[e + 3];
    float g0 = bf2f(h2b[(size_t)s0 * 64 + lane]);
    float g1 = bf2f(h2b[(size_t)s1 * 64 + lane]);
    float g2 = bf2f(h2b[(size_t)s2 * 64 + lane]);
    float g3 = bf2f(h2b[(size_t)s3 * 64 + lane]);
    float w0 = __expf(leaky(as2[s0] + ad) - m);
    float w1 = __expf(leaky(as2[s1] + ad) - m);
    float w2 = __expf(leaky(as2[s2] + ad) - m);
    float w3 = __expf(leaky(as2[s3] + ad) - m);
    denom += (w0 + w1) + (w2 + w3);
    acc += w0 * g0 + w1 * g1 + w2 * g2 + w3 * g3;
  }
  for (; e < end; ++e) {
    int s = ssrc[e];
    float w = __expf(leaky(as2[s] + ad) - m);
    denom += w;
    acc += w * bf2f(h2b[(size_t)s * 64 + lane]);
  }
  hfin[(size_t)wid * 64 + lane] = acc / denom + b2[lane];
}

// ---------------- global mean pool (batch is sorted) ----------------
__global__ void k_pool(const float* __restrict__ hfin, const int* __restrict__ gstart,
                       float* __restrict__ out) {
  int g = blockIdx.x;
  int c = threadIdx.x & 63, r = threadIdx.x >> 6;
  int start = gstart[g], cnt = gstart[g + 1] - start;
  float acc = 0.f;
  for (int i = r; i < cnt; i += 4)
    acc += hfin[(size_t)(start + i) * 64 + c];
  __shared__ float red[256];
  red[threadIdx.x] = acc;
  __syncthreads();
  if (r == 0)
    out[g * 64 + c] = (red[c] + red[64 + c] + red[128 + c] + red[192 + c]) /
                      fmaxf((float)cnt, 1.f);
}

// ---------------- launcher ----------------
extern "C" void kernel_launch(void* const* d_in, const int* in_sizes, int n_in,
                              void* d_out, int out_size, void* d_ws, size_t ws_size,
                              hipStream_t stream) {
  const float* x        = (const float*)d_in[0];
  const int*   ei       = (const int*)d_in[1];
  const int*   batch    = (const int*)d_in[2];
  const float* W1       = (const float*)d_in[3];
  const float* att_src1 = (const float*)d_in[4];
  const float* att_dst1 = (const float*)d_in[5];
  const float* b1       = (const float*)d_in[6];
  const float* W2       = (const float*)d_in[7];
  const float* att_src2 = (const float*)d_in[8];
  const float* att_dst2 = (const float*)d_in[9];
  const float* b2       = (const float*)d_in[10];
  float* out = (float*)d_out;

  const int N = in_sizes[0] / 128;   // 50000
  const int E = in_sizes[1] / 2;     // 800000
  const int EE = E + N;
  const int* esrc = ei;
  const int* edst = ei + E;

  // workspace carve (256B aligned)
  char* p = (char*)d_ws;
  auto alloc = [&](size_t bytes) -> void* {
    void* r = (void*)p;
    p += (bytes + 255) & ~(size_t)255;
    return r;
  };
  ushort_t* h1b   = (ushort_t*)alloc((size_t)N * 256 * 2);
  float*    hrelu = (float*)alloc((size_t)N * 256 * 4);
  ushort_t* h2b   = (ushort_t*)alloc((size_t)N * 64 * 2);
  float*    hfin  = (float*)alloc((size_t)N * 64 * 4);
  float*    as1   = (float*)alloc((size_t)N * 4 * 4);
  float*    ad1   = (float*)alloc((size_t)N * 4 * 4);
  float*    as2   = (float*)alloc((size_t)N * 4);
  float*    ad2   = (float*)alloc((size_t)N * 4);
  int* deg     = (int*)alloc((size_t)N * 4);
  int* offsets = (int*)alloc((size_t)(N + 1) * 4);
  int* cursor  = (int*)alloc((size_t)N * 4);
  int* ssrc    = (int*)alloc((size_t)EE * 4);
  int* gstart  = (int*)alloc(65 * 4);

  // --- build dst-sorted edge lists (counting sort, recomputed every call) ---
  k_zero_i32<<<(N + 255) / 256, 256, 0, stream>>>(deg, N);
  k_hist<<<1024, 256, 0, stream>>>(edst, E, N, deg);
  k_gbounds<<<256, 256, 0, stream>>>(batch, N, 64, gstart);
  k_scan<<<1, 1024, 0, stream>>>(deg, N, offsets, cursor);
  k_scatter<<<1024, 256, 0, stream>>>(esrc, edst, E, N, cursor, ssrc);

  // --- layer 1: fused GEMM + logits -> h1b/as1/ad1 ---
  k_gemm_att<<<dim3((N + 127) / 128, 4), 256, 0, stream>>>(
      x, W1, att_src1, att_dst1, h1b, as1, ad1, N, 256, 128, 4);
  int wave_blocks = (N * 64 + 255) / 256;
  k_agg1<<<wave_blocks, 256, 0, stream>>>(h1b, as1, ad1, offsets, ssrc, b1, hrelu, N);

  // --- layer 2: fused GEMM + logits -> h2b/as2/ad2 ---
  k_gemm_att<<<dim3((N + 127) / 128, 1), 256, 0, stream>>>(
      hrelu, W2, att_src2, att_dst2, h2b, as2, ad2, N, 64, 256, 1);
  k_agg2<<<wave_blocks, 256, 0, stream>>>(h2b, as2, ad2, offsets, ssrc, b2, hfin, N);

  // --- global mean pool ---
  k_pool<<<64, 256, 0, stream>>>(hfin, gstart, out);
}

// Round 6
// 424.666 us; speedup vs baseline: 1.1384x; 1.1384x over previous
//
#include <hip/hip_runtime.h>
#include <math.h>

// ---------------- problem constants (match reference) ----------------
// N=50000, F_IN=128, HID=64, HEADS1=4 (C1=256), NUM_GRAPHS=64, slope=0.2

typedef unsigned short ushort_t;

__device__ inline float bf2f(ushort_t u) { return __uint_as_float((unsigned)u << 16); }
__device__ inline ushort_t f2bf(float x) {            // round-to-nearest-even
  unsigned b = __float_as_uint(x);
  return (ushort_t)((b + 0x7fff + ((b >> 16) & 1)) >> 16);
}
__device__ inline float leaky(float v) { return (v > 0.f) ? v : 0.2f * v; }

// ---------------- small utility kernels ----------------
__global__ void k_zero_i32(int* __restrict__ p, int n) {
  int i = blockIdx.x * blockDim.x + threadIdx.x;
  if (i < n) p[i] = 0;
}

__global__ void k_hist(const int* __restrict__ edst, int E, int N, int* __restrict__ deg) {
  int stride = gridDim.x * blockDim.x;
  int EE = E + N;
  for (int i = blockIdx.x * blockDim.x + threadIdx.x; i < EE; i += stride) {
    int d = (i < E) ? edst[i] : (i - E);
    atomicAdd(&deg[d], 1);
  }
}

// graph boundaries from SORTED batch array -> gstart[0..G], no atomics
__global__ void k_gbounds(const int* __restrict__ batch, int N, int G,
                          int* __restrict__ gstart) {
  int stride = gridDim.x * blockDim.x;
  for (int i = blockIdx.x * blockDim.x + threadIdx.x; i < N; i += stride) {
    int b = batch[i];
    int bp = (i == 0) ? -1 : batch[i - 1];
    for (int g = bp + 1; g <= b; ++g) gstart[g] = i;
    if (i == N - 1)
      for (int g = b + 1; g <= G; ++g) gstart[g] = N;
  }
}

// single-block exclusive scan; wave-shfl scan + cross-wave LDS, 2 barriers/chunk
__global__ void k_scan(const int* __restrict__ deg, int n,
                       int* __restrict__ offsets, int* __restrict__ cursor) {
  __shared__ int wsum[16];
  __shared__ int carry_s;
  int tid = threadIdx.x, lane = tid & 63, wv = tid >> 6;
  if (tid == 0) carry_s = 0;
  __syncthreads();
  for (int base = 0; base < n; base += 1024) {
    int i = base + tid;
    int v = (i < n) ? deg[i] : 0;
    int x = v;
    #pragma unroll
    for (int off = 1; off < 64; off <<= 1) {
      int t = __shfl_up(x, off);
      if (lane >= off) x += t;
    }
    if (lane == 63) wsum[wv] = x;
    __syncthreads();
    if (wv == 0 && lane < 16) {
      int s = wsum[lane];
      #pragma unroll
      for (int off = 1; off < 16; off <<= 1) {
        int t = __shfl_up(s, off);
        if (lane >= off) s += t;
      }
      wsum[lane] = s;
    }
    __syncthreads();
    int wbase = (wv == 0) ? 0 : wsum[wv - 1];
    int incl = carry_s + wbase + x;
    if (i < n) { int o = incl - v; offsets[i] = o; cursor[i] = o; }
    __syncthreads();
    if (tid == 1023) carry_s = incl;
    __syncthreads();
  }
  if (tid == 0) offsets[n] = carry_s;
}

__global__ void k_scatter(const int* __restrict__ esrc, const int* __restrict__ edst,
                          int E, int N, int* __restrict__ cursor, int* __restrict__ ssrc) {
  int stride = gridDim.x * blockDim.x;
  int EE = E + N;
  for (int i = blockIdx.x * blockDim.x + threadIdx.x; i < EE; i += stride) {
    int d, s;
    if (i < E) { d = edst[i]; s = esrc[i]; }
    else       { d = i - E;   s = i - E;   }
    int pos = atomicAdd(&cursor[d], 1);
    ssrc[pos] = s;
  }
}

// ---------------- fused f32 GEMM + attention logits + bf16 output ----------------
// C = A[M,K] @ B[K,Nn]; 64x64 tile, 4x4 microtile, K-step 32, single-buffer LDS,
// register prefetch of next k-tile. As pad 68 -> b128-aligned reads, 2-way writes.
// Epilogue: per-row head dots with a_src/a_dst (width-16 shfl), bf16 h + as/ad out.
__global__ __launch_bounds__(256)
void k_gemm_att(const float* __restrict__ A, const float* __restrict__ B,
                const float* __restrict__ a_srcW, const float* __restrict__ a_dstW,
                ushort_t* __restrict__ hb, float* __restrict__ as_,
                float* __restrict__ ad_, int M, int Nn, int K, int H) {
  __shared__ float As[32][68];   // [kk][row]; 68 -> 16B-aligned b128 reads
  __shared__ float Bs[32][64];   // [kk][col]; b128 reads 2-way (free)
  const int tid = threadIdx.x;
  const int tx = tid & 15, ty = tid >> 4;
  const int row0 = blockIdx.x * 64, col0 = blockIdx.y * 64;
  const int head = col0 >> 6;

  // staging coords: A: row ar (0..63), kc = 4*(tid>>6) (+16 on pass 1)
  const int ar = tid & 63, ac4 = (tid >> 6) << 2;
  // B: row kb (0..15, +16), col bc4
  const int kb = tid >> 4, bc4 = (tid & 15) << 2;

  float4 pa[2], pb[2];
  auto gload = [&](int k0) {
    const int gr = row0 + ar;
    #pragma unroll
    for (int p = 0; p < 2; ++p) {
      int kc = ac4 + p * 16;
      pa[p] = (gr < M) ? *(const float4*)(A + (size_t)gr * K + k0 + kc)
                       : make_float4(0.f, 0.f, 0.f, 0.f);
      pb[p] = *(const float4*)(B + (size_t)(k0 + kb + p * 16) * Nn + col0 + bc4);
    }
  };
  auto swrite = [&]() {
    #pragma unroll
    for (int p = 0; p < 2; ++p) {
      int kc = ac4 + p * 16;
      As[kc + 0][ar] = pa[p].x;          // bank=(4kc+ar)%32, ar spans 0..63: 2-way
      As[kc + 1][ar] = pa[p].y;
      As[kc + 2][ar] = pa[p].z;
      As[kc + 3][ar] = pa[p].w;
      *(float4*)&Bs[kb + p * 16][bc4] = pb[p];
    }
  };

  float acc[4][4] = {};
  gload(0);
  const int T = K >> 5;
  for (int t = 0; t < T; ++t) {
    swrite();
    __syncthreads();
    if (t + 1 < T) gload((t + 1) << 5);   // prefetch next k-tile into regs
    #pragma unroll
    for (int kk = 0; kk < 32; ++kk) {
      float4 a = *(const float4*)&As[kk][ty * 4];   // broadcast, conflict-free
      float4 b = *(const float4*)&Bs[kk][tx * 4];   // 2-way (free)
      acc[0][0] += a.x * b.x; acc[0][1] += a.x * b.y; acc[0][2] += a.x * b.z; acc[0][3] += a.x * b.w;
      acc[1][0] += a.y * b.x; acc[1][1] += a.y * b.y; acc[1][2] += a.y * b.z; acc[1][3] += a.y * b.w;
      acc[2][0] += a.z * b.x; acc[2][1] += a.z * b.y; acc[2][2] += a.z * b.z; acc[2][3] += a.z * b.w;
      acc[3][0] += a.w * b.x; acc[3][1] += a.w * b.y; acc[3][2] += a.w * b.z; acc[3][3] += a.w * b.w;
    }
    __syncthreads();
  }

  // epilogue: bf16 store + per-head attention logits
  float4 sv = *(const float4*)(a_srcW + head * 64 + tx * 4);
  float4 dv = *(const float4*)(a_dstW + head * 64 + tx * 4);
  #pragma unroll
  for (int i = 0; i < 4; ++i) {
    int gr = row0 + ty * 4 + i;
    float ps = acc[i][0] * sv.x + acc[i][1] * sv.y + acc[i][2] * sv.z + acc[i][3] * sv.w;
    float pd = acc[i][0] * dv.x + acc[i][1] * dv.y + acc[i][2] * dv.z + acc[i][3] * dv.w;
    #pragma unroll
    for (int off = 1; off < 16; off <<= 1) {
      ps += __shfl_xor(ps, off);
      pd += __shfl_xor(pd, off);
    }
    if (gr < M) {
      ushort4 hv;
      hv.x = f2bf(acc[i][0]); hv.y = f2bf(acc[i][1]);
      hv.z = f2bf(acc[i][2]); hv.w = f2bf(acc[i][3]);
      *(ushort4*)(hb + (size_t)gr * Nn + col0 + tx * 4) = hv;
      if (tx == 0) { as_[gr * H + head] = ps; ad_[gr * H + head] = pd; }
    }
  }
}

// ---------------- layer-1 segment softmax + aggregation ----------------
__global__ void k_agg1(const ushort_t* __restrict__ h1b, const float* __restrict__ as1,
                       const float* __restrict__ ad1, const int* __restrict__ offs,
                       const int* __restrict__ ssrc, const float* __restrict__ b1,
                       float* __restrict__ hrelu, int N) {
  int gt = blockIdx.x * blockDim.x + threadIdx.x;
  int wid = gt >> 6, lane = gt & 63;
  if (wid >= N) return;
  int head = lane >> 4, sub = lane & 15, coff = sub << 2;
  int start = offs[wid], end = offs[wid + 1];
  float ad = ad1[wid * 4 + head];

  float m = -INFINITY;
  for (int e = start + sub; e < end; e += 16) {
    int s = ssrc[e];
    m = fmaxf(m, leaky(as1[s * 4 + head] + ad));
  }
  #pragma unroll
  for (int off = 1; off < 16; off <<= 1) m = fmaxf(m, __shfl_xor(m, off));

  float denom = 0.f;
  float4 acc = make_float4(0.f, 0.f, 0.f, 0.f);
  int e = start;
  for (; e + 4 <= end; e += 4) {
    int s0 = ssrc[e], s1 = ssrc[e + 1], s2 = ssrc[e + 2], s3 = ssrc[e + 3];
    ushort4 g0 = *(const ushort4*)(h1b + (size_t)s0 * 256 + head * 64 + coff);
    ushort4 g1 = *(const ushort4*)(h1b + (size_t)s1 * 256 + head * 64 + coff);
    ushort4 g2 = *(const ushort4*)(h1b + (size_t)s2 * 256 + head * 64 + coff);
    ushort4 g3 = *(const ushort4*)(h1b + (size_t)s3 * 256 + head * 64 + coff);
    float w0 = __expf(leaky(as1[s0 * 4 + head] + ad) - m);
    float w1 = __expf(leaky(as1[s1 * 4 + head] + ad) - m);
    float w2 = __expf(leaky(as1[s2 * 4 + head] + ad) - m);
    float w3 = __expf(leaky(as1[s3 * 4 + head] + ad) - m);
    denom += (w0 + w1) + (w2 + w3);
    acc.x += w0 * bf2f(g0.x) + w1 * bf2f(g1.x) + w2 * bf2f(g2.x) + w3 * bf2f(g3.x);
    acc.y += w0 * bf2f(g0.y) + w1 * bf2f(g1.y) + w2 * bf2f(g2.y) + w3 * bf2f(g3.y);
    acc.z += w0 * bf2f(g0.z) + w1 * bf2f(g1.z) + w2 * bf2f(g2.z) + w3 * bf2f(g3.z);
    acc.w += w0 * bf2f(g0.w) + w1 * bf2f(g1.w) + w2 * bf2f(g2.w) + w3 * bf2f(g3.w);
  }
  for (; e < end; ++e) {
    int s = ssrc[e];
    float w = __expf(leaky(as1[s * 4 + head] + ad) - m);
    ushort4 g = *(const ushort4*)(h1b + (size_t)s * 256 + head * 64 + coff);
    denom += w;
    acc.x += w * bf2f(g.x); acc.y += w * bf2f(g.y);
    acc.z += w * bf2f(g.z); acc.w += w * bf2f(g.w);
  }
  float inv = 1.f / denom;
  float4 bv = *(const float4*)(b1 + head * 64 + coff);
  float4 o;
  o.x = fmaxf(acc.x * inv + bv.x, 0.f);
  o.y = fmaxf(acc.y * inv + bv.y, 0.f);
  o.z = fmaxf(acc.z * inv + bv.z, 0.f);
  o.w = fmaxf(acc.w * inv + bv.w, 0.f);
  *(float4*)(hrelu + (size_t)wid * 256 + head * 64 + coff) = o;
}

// ---------------- layer-2 segment softmax + aggregation ----------------
__global__ void k_agg2(const ushort_t* __restrict__ h2b, const float* __restrict__ as2,
                       const float* __restrict__ ad2, const int* __restrict__ offs,
                       const int* __restrict__ ssrc, const float* __restrict__ b2,
                       float* __restrict__ hfin, int N) {
  int gt = blockIdx.x * blockDim.x + threadIdx.x;
  int wid = gt >> 6, lane = gt & 63;
  if (wid >= N) return;
  int start = offs[wid], end = offs[wid + 1];
  float ad = ad2[wid];

  float m = -INFINITY;
  for (int e = start + lane; e < end; e += 64) {
    m = fmaxf(m, leaky(as2[ssrc[e]] + ad));
  }
  #pragma unroll
  for (int off = 1; off < 64; off <<= 1) m = fmaxf(m, __shfl_xor(m, off));

  float denom = 0.f, acc = 0.f;
  int e = start;
  for (; e + 4 <= end; e += 4) {
    int s0 = ssrc[e], s1 = ssrc[e + 1], s2 = ssrc[e + 2], s3 = ssrc[e + 3];
    float g0 = bf2f(h2b[(size_t)s0 * 64 + lane]);
    float g1 = bf2f(h2b[(size_t)s1 * 64 + lane]);
    float g2 = bf2f(h2b[(size_t)s2 * 64 + lane]);
    float g3 = bf2f(h2b[(size_t)s3 * 64 + lane]);
    float w0 = __expf(leaky(as2[s0] + ad) - m);
    float w1 = __expf(leaky(as2[s1] + ad) - m);
    float w2 = __expf(leaky(as2[s2] + ad) - m);
    float w3 = __expf(leaky(as2[s3] + ad) - m);
    denom += (w0 + w1) + (w2 + w3);
    acc += w0 * g0 + w1 * g1 + w2 * g2 + w3 * g3;
  }
  for (; e < end; ++e) {
    int s = ssrc[e];
    float w = __expf(leaky(as2[s] + ad) - m);
    denom += w;
    acc += w * bf2f(h2b[(size_t)s * 64 + lane]);
  }
  hfin[(size_t)wid * 64 + lane] = acc / denom + b2[lane];
}

// ---------------- global mean pool (batch is sorted) ----------------
__global__ void k_pool(const float* __restrict__ hfin, const int* __restrict__ gstart,
                       float* __restrict__ out) {
  int g = blockIdx.x;
  int c = threadIdx.x & 63, r = threadIdx.x >> 6;
  int start = gstart[g], cnt = gstart[g + 1] - start;
  float acc = 0.f;
  for (int i = r; i < cnt; i += 4)
    acc += hfin[(size_t)(start + i) * 64 + c];
  __shared__ float red[256];
  red[threadIdx.x] = acc;
  __syncthreads();
  if (r == 0)
    out[g * 64 + c] = (red[c] + red[64 + c] + red[128 + c] + red[192 + c]) /
                      fmaxf((float)cnt, 1.f);
}

// ---------------- launcher ----------------
extern "C" void kernel_launch(void* const* d_in, const int* in_sizes, int n_in,
                              void* d_out, int out_size, void* d_ws, size_t ws_size,
                              hipStream_t stream) {
  const float* x        = (const float*)d_in[0];
  const int*   ei       = (const int*)d_in[1];
  const int*   batch    = (const int*)d_in[2];
  const float* W1       = (const float*)d_in[3];
  const float* att_src1 = (const float*)d_in[4];
  const float* att_dst1 = (const float*)d_in[5];
  const float* b1       = (const float*)d_in[6];
  const float* W2       = (const float*)d_in[7];
  const float* att_src2 = (const float*)d_in[8];
  const float* att_dst2 = (const float*)d_in[9];
  const float* b2       = (const float*)d_in[10];
  float* out = (float*)d_out;

  const int N = in_sizes[0] / 128;   // 50000
  const int E = in_sizes[1] / 2;     // 800000
  const int EE = E + N;
  const int* esrc = ei;
  const int* edst = ei + E;

  // workspace carve (256B aligned)
  char* p = (char*)d_ws;
  auto alloc = [&](size_t bytes) -> void* {
    void* r = (void*)p;
    p += (bytes + 255) & ~(size_t)255;
    return r;
  };
  ushort_t* h1b   = (ushort_t*)alloc((size_t)N * 256 * 2);
  float*    hrelu = (float*)alloc((size_t)N * 256 * 4);
  ushort_t* h2b   = (ushort_t*)alloc((size_t)N * 64 * 2);
  float*    hfin  = (float*)alloc((size_t)N * 64 * 4);
  float*    as1   = (float*)alloc((size_t)N * 4 * 4);
  float*    ad1   = (float*)alloc((size_t)N * 4 * 4);
  float*    as2   = (float*)alloc((size_t)N * 4);
  float*    ad2   = (float*)alloc((size_t)N * 4);
  int* deg     = (int*)alloc((size_t)N * 4);
  int* offsets = (int*)alloc((size_t)(N + 1) * 4);
  int* cursor  = (int*)alloc((size_t)N * 4);
  int* ssrc    = (int*)alloc((size_t)EE * 4);
  int* gstart  = (int*)alloc(65 * 4);

  // --- build dst-sorted edge lists (counting sort, recomputed every call) ---
  k_zero_i32<<<(N + 255) / 256, 256, 0, stream>>>(deg, N);
  k_hist<<<1024, 256, 0, stream>>>(edst, E, N, deg);
  k_gbounds<<<256, 256, 0, stream>>>(batch, N, 64, gstart);
  k_scan<<<1, 1024, 0, stream>>>(deg, N, offsets, cursor);
  k_scatter<<<1024, 256, 0, stream>>>(esrc, edst, E, N, cursor, ssrc);

  // --- layer 1: fused GEMM + logits -> h1b/as1/ad1 ---
  k_gemm_att<<<dim3((N + 63) / 64, 4), 256, 0, stream>>>(
      x, W1, att_src1, att_dst1, h1b, as1, ad1, N, 256, 128, 4);
  int wave_blocks = (N * 64 + 255) / 256;
  k_agg1<<<wave_blocks, 256, 0, stream>>>(h1b, as1, ad1, offsets, ssrc, b1, hrelu, N);

  // --- layer 2: fused GEMM + logits -> h2b/as2/ad2 ---
  k_gemm_att<<<dim3((N + 63) / 64, 1), 256, 0, stream>>>(
      hrelu, W2, att_src2, att_dst2, h2b, as2, ad2, N, 64, 256, 1);
  k_agg2<<<wave_blocks, 256, 0, stream>>>(h2b, as2, ad2, offsets, ssrc, b2, hfin, N);

  // --- global mean pool ---
  k_pool<<<64, 256, 0, stream>>>(hfin, gstart, out);
}

// Round 7
// 372.371 us; speedup vs baseline: 1.2982x; 1.1404x over previous
//
#include <hip/hip_runtime.h>
#include <math.h>

// ---------------- problem constants (match reference) ----------------
// N=50000, F_IN=128, HID=64, HEADS1=4 (C1=256), NUM_GRAPHS=64, slope=0.2

typedef unsigned short ushort_t;
typedef __bf16 bf16x8 __attribute__((ext_vector_type(8)));
typedef float  f32x4  __attribute__((ext_vector_type(4)));

__device__ inline float bf2f(ushort_t u) { return __uint_as_float((unsigned)u << 16); }
__device__ inline ushort_t f2bf(float x) {            // round-to-nearest-even
  unsigned b = __float_as_uint(x);
  return (ushort_t)((b + 0x7fff + ((b >> 16) & 1)) >> 16);
}
__device__ inline float leaky(float v) { return (v > 0.f) ? v : 0.2f * v; }

__device__ inline bf16x8 ldfrag(const ushort_t* p, size_t fl) {
  return *(const bf16x8*)(p + fl * 8);
}
__device__ inline f32x4 mfma16(bf16x8 a, bf16x8 b, f32x4 c) {
  return __builtin_amdgcn_mfma_f32_16x16x32_bf16(a, b, c, 0, 0, 0);
}

// ---------------- small utility kernels ----------------
__global__ void k_zero_i32(int* __restrict__ p, int n) {
  int i = blockIdx.x * blockDim.x + threadIdx.x;
  if (i < n) p[i] = 0;
}

__global__ void k_hist(const int* __restrict__ edst, int E, int N, int* __restrict__ deg) {
  int stride = gridDim.x * blockDim.x;
  int EE = E + N;
  for (int i = blockIdx.x * blockDim.x + threadIdx.x; i < EE; i += stride) {
    int d = (i < E) ? edst[i] : (i - E);
    atomicAdd(&deg[d], 1);
  }
}

__global__ void k_gbounds(const int* __restrict__ batch, int N, int G,
                          int* __restrict__ gstart) {
  int stride = gridDim.x * blockDim.x;
  for (int i = blockIdx.x * blockDim.x + threadIdx.x; i < N; i += stride) {
    int b = batch[i];
    int bp = (i == 0) ? -1 : batch[i - 1];
    for (int g = bp + 1; g <= b; ++g) gstart[g] = i;
    if (i == N - 1)
      for (int g = b + 1; g <= G; ++g) gstart[g] = N;
  }
}

__global__ void k_scan(const int* __restrict__ deg, int n,
                       int* __restrict__ offsets, int* __restrict__ cursor) {
  __shared__ int wsum[16];
  __shared__ int carry_s;
  int tid = threadIdx.x, lane = tid & 63, wv = tid >> 6;
  if (tid == 0) carry_s = 0;
  __syncthreads();
  for (int base = 0; base < n; base += 1024) {
    int i = base + tid;
    int v = (i < n) ? deg[i] : 0;
    int x = v;
    #pragma unroll
    for (int off = 1; off < 64; off <<= 1) {
      int t = __shfl_up(x, off);
      if (lane >= off) x += t;
    }
    if (lane == 63) wsum[wv] = x;
    __syncthreads();
    if (wv == 0 && lane < 16) {
      int s = wsum[lane];
      #pragma unroll
      for (int off = 1; off < 16; off <<= 1) {
        int t = __shfl_up(s, off);
        if (lane >= off) s += t;
      }
      wsum[lane] = s;
    }
    __syncthreads();
    int wbase = (wv == 0) ? 0 : wsum[wv - 1];
    int incl = carry_s + wbase + x;
    if (i < n) { int o = incl - v; offsets[i] = o; cursor[i] = o; }
    __syncthreads();
    if (tid == 1023) carry_s = incl;
    __syncthreads();
  }
  if (tid == 0) offsets[n] = carry_s;
}

__global__ void k_scatter(const int* __restrict__ esrc, const int* __restrict__ edst,
                          int E, int N, int* __restrict__ cursor, int* __restrict__ ssrc) {
  int stride = gridDim.x * blockDim.x;
  int EE = E + N;
  for (int i = blockIdx.x * blockDim.x + threadIdx.x; i < EE; i += stride) {
    int d, s;
    if (i < E) { d = edst[i]; s = esrc[i]; }
    else       { d = i - E;   s = i - E;   }
    int pos = atomicAdd(&cursor[d], 1);
    ssrc[pos] = s;
  }
}

// ---------------- fragment pack kernels ----------------
// frag layout (both A and B use the SAME k-slot convention, so any HW k-order
// cancels): frag-lane fl = (frag*64 + lane); 16B at fl*8 ushorts; lane l holds
// elements j=0..7 with  row/col = (l&15),  k = kt*32 + (l>>4)*8 + j.

// A pack from f32 row-major [M x K], split hi/lo; frags padded to MF m-frags
__global__ void k_packA_f32(const float* __restrict__ A, ushort_t* __restrict__ ah,
                            ushort_t* __restrict__ al, int M, int K, int MF) {
  int KT = K >> 5;
  int total = MF * KT * 64;
  int t = blockIdx.x * blockDim.x + threadIdx.x;
  if (t >= total) return;
  int l = t & 63, fa = t >> 6;
  int mt = fa / KT, kt = fa - mt * KT;
  int row = mt * 16 + (l & 15);
  int k0 = kt * 32 + (l >> 4) * 8;
  float v[8];
  if (row < M) {
    float4 v0 = *(const float4*)(A + (size_t)row * K + k0);
    float4 v1 = *(const float4*)(A + (size_t)row * K + k0 + 4);
    v[0] = v0.x; v[1] = v0.y; v[2] = v0.z; v[3] = v0.w;
    v[4] = v1.x; v[5] = v1.y; v[6] = v1.z; v[7] = v1.w;
  } else {
    #pragma unroll
    for (int j = 0; j < 8; ++j) v[j] = 0.f;
  }
  ushort_t h[8], lo[8];
  #pragma unroll
  for (int j = 0; j < 8; ++j) {
    h[j] = f2bf(v[j]);
    lo[j] = f2bf(v[j] - bf2f(h[j]));
  }
  size_t o = (size_t)t * 8;
  *(ushort4*)(ah + o)     = make_ushort4(h[0], h[1], h[2], h[3]);
  *(ushort4*)(ah + o + 4) = make_ushort4(h[4], h[5], h[6], h[7]);
  *(ushort4*)(al + o)     = make_ushort4(lo[0], lo[1], lo[2], lo[3]);
  *(ushort4*)(al + o + 4) = make_ushort4(lo[4], lo[5], lo[6], lo[7]);
}

// A pack from bf16 row-major [M x K] (hi only; pure permutation copy)
__global__ void k_packA_bf16(const ushort_t* __restrict__ A, ushort_t* __restrict__ ah,
                             int M, int K, int MF) {
  int KT = K >> 5;
  int total = MF * KT * 64;
  int t = blockIdx.x * blockDim.x + threadIdx.x;
  if (t >= total) return;
  int l = t & 63, fa = t >> 6;
  int mt = fa / KT, kt = fa - mt * KT;
  int row = mt * 16 + (l & 15);
  int k0 = kt * 32 + (l >> 4) * 8;
  ushort4 a = make_ushort4(0, 0, 0, 0), b = make_ushort4(0, 0, 0, 0);
  if (row < M) {
    a = *(const ushort4*)(A + (size_t)row * K + k0);
    b = *(const ushort4*)(A + (size_t)row * K + k0 + 4);
  }
  size_t o = (size_t)t * 8;
  *(ushort4*)(ah + o)     = a;
  *(ushort4*)(ah + o + 4) = b;
}

// B pack from f32 row-major [K x Nn], split hi/lo
__global__ void k_packB_f32(const float* __restrict__ B, ushort_t* __restrict__ bh,
                            ushort_t* __restrict__ bl, int K, int Nn) {
  int KT = K >> 5;
  int total = (Nn >> 4) * KT * 64;
  int t = blockIdx.x * blockDim.x + threadIdx.x;
  if (t >= total) return;
  int l = t & 63, fb = t >> 6;
  int nt = fb / KT, kt = fb - nt * KT;
  int col = nt * 16 + (l & 15);
  int k0 = kt * 32 + (l >> 4) * 8;
  ushort_t h[8], lo[8];
  #pragma unroll
  for (int j = 0; j < 8; ++j) {
    float v = B[(size_t)(k0 + j) * Nn + col];
    h[j] = f2bf(v);
    lo[j] = f2bf(v - bf2f(h[j]));
  }
  size_t o = (size_t)t * 8;
  *(ushort4*)(bh + o)     = make_ushort4(h[0], h[1], h[2], h[3]);
  *(ushort4*)(bh + o + 4) = make_ushort4(h[4], h[5], h[6], h[7]);
  *(ushort4*)(bl + o)     = make_ushort4(lo[0], lo[1], lo[2], lo[3]);
  *(ushort4*)(bl + o + 4) = make_ushort4(lo[4], lo[5], lo[6], lo[7]);
}

// ---------------- MFMA GEMM + fused attention logits + bf16 output ----------------
// No LDS, no barriers: frag-layout operands streamed from global.
// Block = 4 waves; wave = 32 rows x 64 cols (one head). WM m-waves x WN n-waves.
// TERMS: 3 = AhBh+AhBl+AlBh (split A+B), 2 = AhBh+AhBl (A hi-only).
template<int KT, int TERMS, int WM>
__global__ __launch_bounds__(256)
void k_gemm_att(const ushort_t* __restrict__ Ah, const ushort_t* __restrict__ Al,
                const ushort_t* __restrict__ Bh, const ushort_t* __restrict__ Bl,
                const float* __restrict__ a_srcW, const float* __restrict__ a_dstW,
                ushort_t* __restrict__ hb, float* __restrict__ as_,
                float* __restrict__ ad_, int M, int Nn, int H) {
  constexpr int WN = 4 / WM;
  const int tid = threadIdx.x;
  const int w = tid >> 6, lane = tid & 63;
  const int wm = w & (WM - 1), wn = w / WM;
  const int m0w = blockIdx.x * (WM * 32) + wm * 32;
  const int n0  = blockIdx.y * (WN * 64) + wn * 64;
  const int head = n0 >> 6;
  const int mt0 = m0w >> 4, nt0 = n0 >> 4;

  // per-frag base pointers (advance 512 ushorts per kt)
  const ushort_t* pAh[2];
  const ushort_t* pAl[2];
  const ushort_t* pBh[4];
  const ushort_t* pBl[4];
  #pragma unroll
  for (int mi = 0; mi < 2; ++mi) {
    size_t fa = (size_t)(mt0 + mi) * KT;
    pAh[mi] = Ah + fa * 512 + (size_t)lane * 8;
    if constexpr (TERMS == 3) pAl[mi] = Al + fa * 512 + (size_t)lane * 8;
  }
  #pragma unroll
  for (int ni = 0; ni < 4; ++ni) {
    size_t fb = (size_t)(nt0 + ni) * KT;
    pBh[ni] = Bh + fb * 512 + (size_t)lane * 8;
    pBl[ni] = Bl + fb * 512 + (size_t)lane * 8;
  }

  f32x4 acc[2][4];
  #pragma unroll
  for (int mi = 0; mi < 2; ++mi)
    #pragma unroll
    for (int ni = 0; ni < 4; ++ni)
      acc[mi][ni] = (f32x4){0.f, 0.f, 0.f, 0.f};

  for (int kt = 0; kt < KT; ++kt) {
    const size_t ko = (size_t)kt * 512;
    bf16x8 ahf[2], alf[2], bhf[4], blf[4];
    #pragma unroll
    for (int mi = 0; mi < 2; ++mi) {
      ahf[mi] = *(const bf16x8*)(pAh[mi] + ko);
      if constexpr (TERMS == 3) alf[mi] = *(const bf16x8*)(pAl[mi] + ko);
    }
    #pragma unroll
    for (int ni = 0; ni < 4; ++ni) {
      bhf[ni] = *(const bf16x8*)(pBh[ni] + ko);
      blf[ni] = *(const bf16x8*)(pBl[ni] + ko);
    }
    #pragma unroll
    for (int mi = 0; mi < 2; ++mi)
      #pragma unroll
      for (int ni = 0; ni < 4; ++ni) {
        if constexpr (TERMS == 3)
          acc[mi][ni] = mfma16(alf[mi], bhf[ni], acc[mi][ni]);
        acc[mi][ni] = mfma16(ahf[mi], blf[ni], acc[mi][ni]);
        acc[mi][ni] = mfma16(ahf[mi], bhf[ni], acc[mi][ni]);
      }
  }

  // epilogue: per-row head dots + bf16 store
  // D mapping: col = (lane&15) + ni*16, row = (lane>>4)*4 + reg + mi*16
  const int c16 = lane & 15, q = lane >> 4;
  float sv[4], dv[4];
  #pragma unroll
  for (int ni = 0; ni < 4; ++ni) {
    sv[ni] = a_srcW[head * 64 + ni * 16 + c16];
    dv[ni] = a_dstW[head * 64 + ni * 16 + c16];
  }
  #pragma unroll
  for (int mi = 0; mi < 2; ++mi) {
    #pragma unroll
    for (int r = 0; r < 4; ++r) {
      int gr = m0w + mi * 16 + q * 4 + r;
      float ps = acc[mi][0][r] * sv[0] + acc[mi][1][r] * sv[1] +
                 acc[mi][2][r] * sv[2] + acc[mi][3][r] * sv[3];
      float pd = acc[mi][0][r] * dv[0] + acc[mi][1][r] * dv[1] +
                 acc[mi][2][r] * dv[2] + acc[mi][3][r] * dv[3];
      #pragma unroll
      for (int off = 1; off < 16; off <<= 1) {
        ps += __shfl_xor(ps, off);
        pd += __shfl_xor(pd, off);
      }
      if (gr < M) {
        #pragma unroll
        for (int ni = 0; ni < 4; ++ni)
          hb[(size_t)gr * Nn + n0 + ni * 16 + c16] = f2bf(acc[mi][ni][r]);
        if (c16 == 0) { as_[gr * H + head] = ps; ad_[gr * H + head] = pd; }
      }
    }
  }
}

// ---------------- layer-1 segment softmax + aggregation (bf16 out) ----------------
__global__ void k_agg1(const ushort_t* __restrict__ h1b, const float* __restrict__ as1,
                       const float* __restrict__ ad1, const int* __restrict__ offs,
                       const int* __restrict__ ssrc, const float* __restrict__ b1,
                       ushort_t* __restrict__ hrelu, int N) {
  int gt = blockIdx.x * blockDim.x + threadIdx.x;
  int wid = gt >> 6, lane = gt & 63;
  if (wid >= N) return;
  int head = lane >> 4, sub = lane & 15, coff = sub << 2;
  int start = offs[wid], end = offs[wid + 1];
  float ad = ad1[wid * 4 + head];

  float m = -INFINITY;
  for (int e = start + sub; e < end; e += 16) {
    int s = ssrc[e];
    m = fmaxf(m, leaky(as1[s * 4 + head] + ad));
  }
  #pragma unroll
  for (int off = 1; off < 16; off <<= 1) m = fmaxf(m, __shfl_xor(m, off));

  float denom = 0.f;
  float4 acc = make_float4(0.f, 0.f, 0.f, 0.f);
  int e = start;
  for (; e + 4 <= end; e += 4) {
    int s0 = ssrc[e], s1 = ssrc[e + 1], s2 = ssrc[e + 2], s3 = ssrc[e + 3];
    ushort4 g0 = *(const ushort4*)(h1b + (size_t)s0 * 256 + head * 64 + coff);
    ushort4 g1 = *(const ushort4*)(h1b + (size_t)s1 * 256 + head * 64 + coff);
    ushort4 g2 = *(const ushort4*)(h1b + (size_t)s2 * 256 + head * 64 + coff);
    ushort4 g3 = *(const ushort4*)(h1b + (size_t)s3 * 256 + head * 64 + coff);
    float w0 = __expf(leaky(as1[s0 * 4 + head] + ad) - m);
    float w1 = __expf(leaky(as1[s1 * 4 + head] + ad) - m);
    float w2 = __expf(leaky(as1[s2 * 4 + head] + ad) - m);
    float w3 = __expf(leaky(as1[s3 * 4 + head] + ad) - m);
    denom += (w0 + w1) + (w2 + w3);
    acc.x += w0 * bf2f(g0.x) + w1 * bf2f(g1.x) + w2 * bf2f(g2.x) + w3 * bf2f(g3.x);
    acc.y += w0 * bf2f(g0.y) + w1 * bf2f(g1.y) + w2 * bf2f(g2.y) + w3 * bf2f(g3.y);
    acc.z += w0 * bf2f(g0.z) + w1 * bf2f(g1.z) + w2 * bf2f(g2.z) + w3 * bf2f(g3.z);
    acc.w += w0 * bf2f(g0.w) + w1 * bf2f(g1.w) + w2 * bf2f(g2.w) + w3 * bf2f(g3.w);
  }
  for (; e < end; ++e) {
    int s = ssrc[e];
    float w = __expf(leaky(as1[s * 4 + head] + ad) - m);
    ushort4 g = *(const ushort4*)(h1b + (size_t)s * 256 + head * 64 + coff);
    denom += w;
    acc.x += w * bf2f(g.x); acc.y += w * bf2f(g.y);
    acc.z += w * bf2f(g.z); acc.w += w * bf2f(g.w);
  }
  float inv = 1.f / denom;
  float4 bv = *(const float4*)(b1 + head * 64 + coff);
  ushort4 o;
  o.x = f2bf(fmaxf(acc.x * inv + bv.x, 0.f));
  o.y = f2bf(fmaxf(acc.y * inv + bv.y, 0.f));
  o.z = f2bf(fmaxf(acc.z * inv + bv.z, 0.f));
  o.w = f2bf(fmaxf(acc.w * inv + bv.w, 0.f));
  *(ushort4*)(hrelu + (size_t)wid * 256 + head * 64 + coff) = o;
}

// ---------------- layer-2 segment softmax + aggregation ----------------
__global__ void k_agg2(const ushort_t* __restrict__ h2b, const float* __restrict__ as2,
                       const float* __restrict__ ad2, const int* __restrict__ offs,
                       const int* __restrict__ ssrc, const float* __restrict__ b2,
                       float* __restrict__ hfin, int N) {
  int gt = blockIdx.x * blockDim.x + threadIdx.x;
  int wid = gt >> 6, lane = gt & 63;
  if (wid >= N) return;
  int start = offs[wid], end = offs[wid + 1];
  float ad = ad2[wid];

  float m = -INFINITY;
  for (int e = start + lane; e < end; e += 64) {
    m = fmaxf(m, leaky(as2[ssrc[e]] + ad));
  }
  #pragma unroll
  for (int off = 1; off < 64; off <<= 1) m = fmaxf(m, __shfl_xor(m, off));

  float denom = 0.f, acc = 0.f;
  int e = start;
  for (; e + 4 <= end; e += 4) {
    int s0 = ssrc[e], s1 = ssrc[e + 1], s2 = ssrc[e + 2], s3 = ssrc[e + 3];
    float g0 = bf2f(h2b[(size_t)s0 * 64 + lane]);
    float g1 = bf2f(h2b[(size_t)s1 * 64 + lane]);
    float g2 = bf2f(h2b[(size_t)s2 * 64 + lane]);
    float g3 = bf2f(h2b[(size_t)s3 * 64 + lane]);
    float w0 = __expf(leaky(as2[s0] + ad) - m);
    float w1 = __expf(leaky(as2[s1] + ad) - m);
    float w2 = __expf(leaky(as2[s2] + ad) - m);
    float w3 = __expf(leaky(as2[s3] + ad) - m);
    denom += (w0 + w1) + (w2 + w3);
    acc += w0 * g0 + w1 * g1 + w2 * g2 + w3 * g3;
  }
  for (; e < end; ++e) {
    int s = ssrc[e];
    float w = __expf(leaky(as2[s] + ad) - m);
    denom += w;
    acc += w * bf2f(h2b[(size_t)s * 64 + lane]);
  }
  hfin[(size_t)wid * 64 + lane] = acc / denom + b2[lane];
}

// ---------------- global mean pool (batch is sorted) ----------------
__global__ void k_pool(const float* __restrict__ hfin, const int* __restrict__ gstart,
                       float* __restrict__ out) {
  int g = blockIdx.x;
  int c = threadIdx.x & 63, r = threadIdx.x >> 6;
  int start = gstart[g], cnt = gstart[g + 1] - start;
  float acc = 0.f;
  for (int i = r; i < cnt; i += 4)
    acc += hfin[(size_t)(start + i) * 64 + c];
  __shared__ float red[256];
  red[threadIdx.x] = acc;
  __syncthreads();
  if (r == 0)
    out[g * 64 + c] = (red[c] + red[64 + c] + red[128 + c] + red[192 + c]) /
                      fmaxf((float)cnt, 1.f);
}

// ---------------- launcher ----------------
extern "C" void kernel_launch(void* const* d_in, const int* in_sizes, int n_in,
                              void* d_out, int out_size, void* d_ws, size_t ws_size,
                              hipStream_t stream) {
  const float* x        = (const float*)d_in[0];
  const int*   ei       = (const int*)d_in[1];
  const int*   batch    = (const int*)d_in[2];
  const float* W1       = (const float*)d_in[3];
  const float* att_src1 = (const float*)d_in[4];
  const float* att_dst1 = (const float*)d_in[5];
  const float* b1       = (const float*)d_in[6];
  const float* W2       = (const float*)d_in[7];
  const float* att_src2 = (const float*)d_in[8];
  const float* att_dst2 = (const float*)d_in[9];
  const float* b2       = (const float*)d_in[10];
  float* out = (float*)d_out;

  const int N = in_sizes[0] / 128;   // 50000
  const int E = in_sizes[1] / 2;     // 800000
  const int EE = E + N;
  const int* esrc = ei;
  const int* edst = ei + E;

  const int GB2 = (N + 127) / 128;       // 391 gemm2 blocks (128 rows)
  const int GB1 = GB2 * 2;               // 782 gemm1 blocks (64 rows)
  const int MF  = GB2 * 8;               // 3128 padded m-frags (rows/16)

  // workspace carve (256B aligned)
  char* p = (char*)d_ws;
  auto alloc = [&](size_t bytes) -> void* {
    void* r = (void*)p;
    p += (bytes + 255) & ~(size_t)255;
    return r;
  };
  ushort_t* A1h  = (ushort_t*)alloc((size_t)MF * 4 * 64 * 16);
  ushort_t* A1l  = (ushort_t*)alloc((size_t)MF * 4 * 64 * 16);
  ushort_t* A2h  = (ushort_t*)alloc((size_t)MF * 8 * 64 * 16);
  ushort_t* B1h  = (ushort_t*)alloc((size_t)16 * 4 * 64 * 16);
  ushort_t* B1l  = (ushort_t*)alloc((size_t)16 * 4 * 64 * 16);
  ushort_t* B2h  = (ushort_t*)alloc((size_t)4 * 8 * 64 * 16);
  ushort_t* B2l  = (ushort_t*)alloc((size_t)4 * 8 * 64 * 16);
  ushort_t* h1b  = (ushort_t*)alloc((size_t)N * 256 * 2);
  ushort_t* hrelu= (ushort_t*)alloc((size_t)N * 256 * 2);
  ushort_t* h2b  = (ushort_t*)alloc((size_t)N * 64 * 2);
  float*    hfin = (float*)alloc((size_t)N * 64 * 4);
  float*    as1  = (float*)alloc((size_t)N * 4 * 4);
  float*    ad1  = (float*)alloc((size_t)N * 4 * 4);
  float*    as2  = (float*)alloc((size_t)N * 4);
  float*    ad2  = (float*)alloc((size_t)N * 4);
  int* deg     = (int*)alloc((size_t)N * 4);
  int* offsets = (int*)alloc((size_t)(N + 1) * 4);
  int* cursor  = (int*)alloc((size_t)N * 4);
  int* ssrc    = (int*)alloc((size_t)EE * 4);
  int* gstart  = (int*)alloc(65 * 4);

  // --- build dst-sorted edge lists (counting sort, recomputed every call) ---
  k_zero_i32<<<(N + 255) / 256, 256, 0, stream>>>(deg, N);
  k_hist<<<1024, 256, 0, stream>>>(edst, E, N, deg);
  k_gbounds<<<256, 256, 0, stream>>>(batch, N, 64, gstart);
  k_scan<<<1, 1024, 0, stream>>>(deg, N, offsets, cursor);
  k_scatter<<<1024, 256, 0, stream>>>(esrc, edst, E, N, cursor, ssrc);

  // --- pack weights (tiny) and x into fragment layout ---
  k_packB_f32<<<16, 256, 0, stream>>>(W1, B1h, B1l, 128, 256);
  k_packB_f32<<<8, 256, 0, stream>>>(W2, B2h, B2l, 256, 64);
  k_packA_f32<<<MF * 4 * 64 / 256, 256, 0, stream>>>(x, A1h, A1l, N, 128, MF);

  // --- layer 1: MFMA GEMM + fused logits -> h1b/as1/ad1 ---
  k_gemm_att<4, 3, 2><<<dim3(GB1, 2), 256, 0, stream>>>(
      A1h, A1l, B1h, B1l, att_src1, att_dst1, h1b, as1, ad1, N, 256, 4);
  int wave_blocks = (N * 64 + 255) / 256;
  k_agg1<<<wave_blocks, 256, 0, stream>>>(h1b, as1, ad1, offsets, ssrc, b1, hrelu, N);

  // --- layer 2: pack hrelu, MFMA GEMM + fused logits -> h2b/as2/ad2 ---
  k_packA_bf16<<<MF * 8 * 64 / 256, 256, 0, stream>>>(hrelu, A2h, N, 256, MF);
  k_gemm_att<8, 2, 4><<<dim3(GB2, 1), 256, 0, stream>>>(
      A2h, nullptr, B2h, B2l, att_src2, att_dst2, h2b, as2, ad2, N, 64, 1);
  k_agg2<<<wave_blocks, 256, 0, stream>>>(h2b, as2, ad2, offsets, ssrc, b2, hfin, N);

  // --- global mean pool ---
  k_pool<<<64, 256, 0, stream>>>(hfin, gstart, out);
}